// Round 3
// baseline (10837.135 us; speedup 1.0000x reference)
//
#include <hip/hip_runtime.h>
#include <math.h>

// ---------------------------------------------------------------------------
// SocialLstm: T=24, N=2048, INPUT_DIM=2, HIDDEN=64, MEDIATE=128, SOCIAL=64,
// OUT_DIM=2, N_SIZE=2, CELL=0.3, T_obs=9, T_pred=19, WIN=9.
//
// R2: (a) gridmatch: masked agents (key 0) excluded from hash insert+probe
//     (they can never match: real p>=4 -> targets q>=3; masked p=(0,0)).
//     Kills the ~205-entry bucket-0 mega-chain that serialized R1 (52us).
// (b) k_step GEMM g[2048x256] = Z[2048x256] @ Wc^T rewritten as bf16 hi/lo
//     split MFMA (Zh*Wh + Zl*Wh + Zh*Wl), 16x16x32. One wave = 16 agents x
//     256 gates; Z-frags + 16 acc tiles in registers; W pre-packed in
//     fragment order (k_init) and streamed coalesced from L2; LSTM epilogue
//     register-local (acc tiles q,q+4,q+8,q+12 = i,f,g,o for same agents).
// ---------------------------------------------------------------------------

#define N_AG   2048
#define HID    64
#define STEPS  20
#define CAP    12

typedef short short8 __attribute__((ext_vector_type(8)));
typedef float f32x4  __attribute__((ext_vector_type(4)));
union FU { uint4 q; short8 v; };

__device__ __forceinline__ unsigned short bf16rne(float x) {
    unsigned u = __float_as_uint(x);
    unsigned r = (u + 0x7fff + ((u >> 16) & 1)) >> 16;
    return (unsigned short)r;
}

// ---------------------------------------------------------------------------
// k_init: copy h0/c, zero tail frames, We (64x64 folded Wsoc), bc, e0,
// and fragment-ordered bf16 hi/lo packs of Wc = [W_ih | W_hh] (256x256):
// whF/wlF[(nt*8+kt)*64 + lane] = uint4 of 8 bf16, gate g = nt*16+(lane&15),
// k = kt*32 + (lane>>4)*8 + j.
// ---------------------------------------------------------------------------
__global__ void k_init(const float* __restrict__ h_in, const float* __restrict__ c_in,
                       const float* __restrict__ Wsoc, const float* __restrict__ bsoc,
                       const float* __restrict__ bih, const float* __restrict__ bhh,
                       const float* __restrict__ Wih, const float* __restrict__ Whh,
                       float* __restrict__ h0, float* __restrict__ cbuf,
                       float* __restrict__ We, float* __restrict__ bc,
                       float* __restrict__ e0, uint4* __restrict__ whF,
                       uint4* __restrict__ wlF, float* __restrict__ otail)
{
    int idx = blockIdx.x * 256 + threadIdx.x;
    if (idx < 131072) { h0[idx] = h_in[idx]; return; }
    idx -= 131072;
    if (idx < 131072) { cbuf[idx] = c_in[idx]; return; }
    idx -= 131072;
    if (idx < 16384)  { otail[idx] = 0.f; return; }   // frames 20..23 of d_out
    idx -= 16384;
    if (idx < 4096) {
        int s = idx >> 6, k = idx & 63;
        float a = 0.f;
        #pragma unroll
        for (int w = 0; w < 9; w++) a += Wsoc[s * 576 + w * 64 + k];
        We[idx] = a; return;
    }
    idx -= 4096;
    if (idx < 256) { bc[idx] = bih[idx] + bhh[idx]; return; }
    idx -= 256;
    if (idx < 64)  { e0[idx] = fmaxf(bsoc[idx], 0.f); return; }
    idx -= 64;
    if (idx < 8192) {
        int nt = idx >> 9, rem = idx & 511, kt = rem >> 6, ln = rem & 63;
        int g  = nt * 16 + (ln & 15);
        int k0 = kt * 32 + (ln >> 4) * 8;
        unsigned uh[4], ul[4];
        #pragma unroll
        for (int w = 0; w < 4; w++) {
            int k = k0 + 2 * w;
            float a = (k < 192)     ? Wih[g * 192 + k]       : Whh[g * 64 + (k - 192)];
            float b = (k + 1 < 192) ? Wih[g * 192 + k + 1]   : Whh[g * 64 + (k + 1 - 192)];
            unsigned short ha = bf16rne(a), hb = bf16rne(b);
            float fa = __uint_as_float(((unsigned)ha) << 16);
            float fb = __uint_as_float(((unsigned)hb) << 16);
            unsigned short la = bf16rne(a - fa), lb = bf16rne(b - fb);
            uh[w] = (unsigned)ha | ((unsigned)hb << 16);
            ul[w] = (unsigned)la | ((unsigned)lb << 16);
        }
        whF[idx] = make_uint4(uh[0], uh[1], uh[2], uh[3]);
        wlF[idx] = make_uint4(ul[0], ul[1], ul[2], ul[3]);
        return;
    }
}

// ---------------------------------------------------------------------------
// k_gridmatch: one block per step t. Exact fp32 key calc, then O(N) hash
// match. Masked agents (key 0) are NOT inserted and NOT probed.
// ---------------------------------------------------------------------------
__device__ __forceinline__ int khash(int k) {
    return (int)(((unsigned)k * 2654435761u) >> 21);   // 11-bit bucket
}

__global__ void k_gridmatch(const float* __restrict__ X, const float* __restrict__ masks,
                            int* __restrict__ mcnt, int* __restrict__ midx)
{
    int t = blockIdx.x;
    int tid = threadIdx.x;
    __shared__ float red[256];
    __shared__ int kk[N_AG];
    __shared__ int head[N_AG];
    __shared__ int nxt[N_AG];
    const float* Xt = X + t * N_AG * 2;

    float mnx = 1e30f, mny = 1e30f;
    for (int i = tid; i < N_AG; i += 256) {
        mnx = fminf(mnx, Xt[2 * i]);
        mny = fminf(mny, Xt[2 * i + 1]);
    }
    red[tid] = mnx; __syncthreads();
    for (int s = 128; s > 0; s >>= 1) { if (tid < s) red[tid] = fminf(red[tid], red[tid + s]); __syncthreads(); }
    float ltx = red[0]; __syncthreads();
    red[tid] = mny; __syncthreads();
    for (int s = 128; s > 0; s >>= 1) { if (tid < s) red[tid] = fminf(red[tid], red[tid + s]); __syncthreads(); }
    float lty = red[0]; __syncthreads();

    ltx -= 1.2f;   // margin = 2*N_SIZE*CELL
    lty -= 1.2f;

    for (int i = tid; i < N_AG; i += 256) {
        float m = masks[t * N_AG + i];
        int px = (int)floorf((Xt[2 * i]     - ltx) / 0.3f);
        int py = (int)floorf((Xt[2 * i + 1] - lty) / 0.3f);
        int im = (int)m;
        px *= im; py *= im;
        kk[i] = px * 65536 + py;   // masked -> 0; real agents have px,py >= 4
        head[i] = -1;
    }
    __syncthreads();

    // insert only real agents
    for (int j = tid; j < N_AG; j += 256) {
        int kj = kk[j];
        if (kj != 0) {
            int h = khash(kj);
            nxt[j] = atomicExch(&head[h], j);
        }
    }
    __syncthreads();

    // probe only real agents
    for (int i = tid; i < N_AG; i += 256) {
        int ki = kk[i];
        int cnt = 0;
        int base = (t * N_AG + i) * CAP;
        if (ki != 0) {
            int tkey = ki - 65537;
            int lst[CAP];
            for (int j = head[khash(tkey)]; j >= 0; j = nxt[j]) {
                if (kk[j] == tkey) { if (cnt < CAP) lst[cnt] = j; cnt++; }
            }
            if (cnt > CAP) cnt = CAP;
            for (int a = 1; a < cnt; a++) {           // ascending j = ref sum order
                int v = lst[a]; int b = a - 1;
                while (b >= 0 && lst[b] > v) { lst[b + 1] = lst[b]; b--; }
                lst[b + 1] = v;
            }
            for (int a = 0; a < cnt; a++) midx[base + a] = lst[a];
        }
        mcnt[t * N_AG + i] = cnt;
    }
}

// ---------------------------------------------------------------------------
// k_step: one recurrence step. 128 blocks x 64 threads (1 wave = 16 agents).
//  z-prep: z = [r(128)|e(64)|h(64)] fp32 -> LDS zs[16][260] (pad kills
//          the 16-way frag-read bank conflict).
//  frags:  Zh/Zl bf16 hi/lo A-fragments in regs (8 ktiles x 4 VGPR x 2).
//  GEMM:   16 ntiles x 8 ktiles x 3 MFMA (ZhWh + ZlWh + ZhWl), acc in regs.
//  epilogue: acc[q],acc[q+4],acc[q+8],acc[q+12] = i,f,g,o gates for the same
//          agents (rows quad*4+r, hid q*16+col) -> LSTM in regs -> h/c/out.
// ---------------------------------------------------------------------------
__global__ __launch_bounds__(64) void k_step(
    int t,
    const float* __restrict__ rsrc,      // [N,2]: X[t] (t<=10) or out[t-2]
    const float* __restrict__ masks,
    const float* __restrict__ Win, const float* __restrict__ bin,
    const float* __restrict__ bsoc,
    const float* __restrict__ Wout, const float* __restrict__ bout,
    const float* __restrict__ We, const float* __restrict__ e0,
    const float* __restrict__ bc,
    const uint4* __restrict__ whF, const uint4* __restrict__ wlF,
    const int* __restrict__ mcnt, const int* __restrict__ midx,
    const float* __restrict__ hprev, float* __restrict__ hnext,
    float* __restrict__ cbuf, float* __restrict__ out)
{
    __shared__ __align__(16) float zs[16][260];
    __shared__ float hs[16][68];
    __shared__ float cvs[64];

    const int lane  = threadIdx.x;
    const int wbase = blockIdx.x * 16;

    // hoisted per-lane constants
    const float wr0 = Win[2 * lane],        wr1 = Win[2 * lane + 1];
    const float wr2 = Win[2 * (lane + 64)], wr3 = Win[2 * (lane + 64) + 1];
    const float bi0 = bin[lane], bi1 = bin[lane + 64];
    const float e0l = e0[lane];

    // ---- z-prep: 16 agents sequentially, 64 lanes each ----
    for (int a = 0; a < 16; a++) {
        int agent = wbase + a;
        float px = rsrc[2 * agent], py = rsrc[2 * agent + 1];
        zs[a][lane]      = fmaxf(wr0 * px + wr1 * py + bi0, 0.f);
        zs[a][lane + 64] = fmaxf(wr2 * px + wr3 * py + bi1, 0.f);
        zs[a][192 + lane] = hprev[agent * HID + lane];

        int cnt = mcnt[t * N_AG + agent];
        float m = masks[t * N_AG + agent];
        if (cnt == 0 || m == 0.f) {
            zs[a][128 + lane] = e0l;
        } else {
            int base = (t * N_AG + agent) * CAP;
            float cv = 0.f;
            for (int n = 0; n < cnt; n++) cv += hprev[midx[base + n] * HID + lane];
            cvs[lane] = cv;
            __syncthreads();
            float acc = bsoc[lane];
            #pragma unroll 4
            for (int k = 0; k < 64; k += 4) {
                float4 c4 = *(const float4*)&cvs[k];
                float4 w4 = *(const float4*)&We[lane * 64 + k];
                acc += c4.x * w4.x + c4.y * w4.y + c4.z * w4.z + c4.w * w4.w;
            }
            zs[a][128 + lane] = fmaxf(acc, 0.f);
            __syncthreads();
        }
    }
    __syncthreads();

    // ---- build Zh/Zl A-fragments ----
    const int mA = lane & 15, quad = lane >> 4;
    short8 zh[8], zl[8];
    #pragma unroll
    for (int kt = 0; kt < 8; kt++) {
        const float* zp = &zs[mA][kt * 32 + quad * 8];
        FU fh, fl;
        unsigned uh[4], ul[4];
        #pragma unroll
        for (int w = 0; w < 4; w++) {
            float v0 = zp[2 * w], v1 = zp[2 * w + 1];
            unsigned short h0 = bf16rne(v0), h1 = bf16rne(v1);
            float f0 = __uint_as_float(((unsigned)h0) << 16);
            float f1 = __uint_as_float(((unsigned)h1) << 16);
            unsigned short l0 = bf16rne(v0 - f0), l1 = bf16rne(v1 - f1);
            uh[w] = (unsigned)h0 | ((unsigned)h1 << 16);
            ul[w] = (unsigned)l0 | ((unsigned)l1 << 16);
        }
        fh.q = make_uint4(uh[0], uh[1], uh[2], uh[3]);
        fl.q = make_uint4(ul[0], ul[1], ul[2], ul[3]);
        zh[kt] = fh.v;
        zl[kt] = fl.v;
    }

    // ---- GEMM: 16 ntiles, 2 interleaved for MFMA ILP ----
    f32x4 acc[16];
    for (int nt = 0; nt < 16; nt += 2) {
        f32x4 a0 = {0.f, 0.f, 0.f, 0.f};
        f32x4 a1 = {0.f, 0.f, 0.f, 0.f};
        const uint4* wh0p = whF + (nt * 8) * 64 + lane;
        const uint4* wl0p = wlF + (nt * 8) * 64 + lane;
        #pragma unroll 2
        for (int kt = 0; kt < 8; kt++) {
            FU wh0, wl0, wh1, wl1;
            wh0.q = wh0p[kt * 64];
            wl0.q = wl0p[kt * 64];
            wh1.q = wh0p[(8 + kt) * 64];
            wl1.q = wl0p[(8 + kt) * 64];
            a0 = __builtin_amdgcn_mfma_f32_16x16x32_bf16(zh[kt], wh0.v, a0, 0, 0, 0);
            a1 = __builtin_amdgcn_mfma_f32_16x16x32_bf16(zh[kt], wh1.v, a1, 0, 0, 0);
            a0 = __builtin_amdgcn_mfma_f32_16x16x32_bf16(zl[kt], wh0.v, a0, 0, 0, 0);
            a1 = __builtin_amdgcn_mfma_f32_16x16x32_bf16(zl[kt], wh1.v, a1, 0, 0, 0);
            a0 = __builtin_amdgcn_mfma_f32_16x16x32_bf16(zh[kt], wl0.v, a0, 0, 0, 0);
            a1 = __builtin_amdgcn_mfma_f32_16x16x32_bf16(zh[kt], wl1.v, a1, 0, 0, 0);
        }
        acc[nt] = a0; acc[nt + 1] = a1;
    }

    // ---- LSTM epilogue (register-local gate regrouping) ----
    const int col = lane & 15;
    #pragma unroll
    for (int q = 0; q < 4; q++) {
        int hid = q * 16 + col;
        float bci = bc[hid], bcf = bc[64 + hid], bcg = bc[128 + hid], bco = bc[192 + hid];
        #pragma unroll
        for (int r = 0; r < 4; r++) {
            int m = quad * 4 + r;
            int agent = wbase + m;
            float gi = acc[q][r]      + bci;
            float gf = acc[q + 4][r]  + bcf;
            float gg = acc[q + 8][r]  + bcg;
            float go = acc[q + 12][r] + bco;
            float cp = cbuf[agent * HID + hid];
            float si = 1.f / (1.f + expf(-gi));
            float sf = 1.f / (1.f + expf(-gf));
            float so = 1.f / (1.f + expf(-go));
            float cn = sf * cp + si * tanhf(gg);
            float hn = so * tanhf(cn);
            cbuf[agent * HID + hid]  = cn;
            hnext[agent * HID + hid] = hn;
            hs[m][hid] = hn;
        }
    }
    __syncthreads();

    // ---- out = (h @ W_out.T + b_out) * mask ----
    if (lane < 32) {
        int a2 = lane >> 1, d = lane & 1;
        int agent2 = wbase + a2;
        float acc2 = bout[d];
        #pragma unroll 4
        for (int k = 0; k < 64; k += 4) {
            float4 h4 = *(const float4*)&hs[a2][k];
            float4 w4 = *(const float4*)&Wout[d * 64 + k];
            acc2 += h4.x * w4.x + h4.y * w4.y + h4.z * w4.z + h4.w * w4.w;
        }
        out[(t * N_AG + agent2) * 2 + d] = acc2 * masks[t * N_AG + agent2];
    }
}

// ---------------------------------------------------------------------------
extern "C" void kernel_launch(void* const* d_in, const int* in_sizes, int n_in,
                              void* d_out, int out_size, void* d_ws, size_t ws_size,
                              hipStream_t stream)
{
    const float* X     = (const float*)d_in[0];
    const float* masks = (const float*)d_in[1];
    const float* h_in  = (const float*)d_in[2];
    const float* c_in  = (const float*)d_in[3];
    // d_in[4] = Y (unused), d_in[5] = T_obs (=9), d_in[6] = T_pred (=19)
    const float* Win   = (const float*)d_in[7];
    const float* bin   = (const float*)d_in[8];
    const float* Wsoc  = (const float*)d_in[9];
    const float* bsoc  = (const float*)d_in[10];
    const float* Wih   = (const float*)d_in[11];
    const float* Whh   = (const float*)d_in[12];
    const float* bih   = (const float*)d_in[13];
    const float* bhh   = (const float*)d_in[14];
    const float* Wout  = (const float*)d_in[15];
    const float* bout  = (const float*)d_in[16];
    float* out = (float*)d_out;

    // workspace layout (uint4-aligned first)
    uint4* whF = (uint4*)d_ws;            // 8192
    uint4* wlF = whF + 8192;              // 8192
    float* h0  = (float*)(wlF + 8192);    // 131072
    float* h1  = h0 + 131072;             // 131072
    float* cb  = h1 + 131072;             // 131072
    float* We  = cb + 131072;             // 4096
    float* bc  = We + 4096;               // 256
    float* e0  = bc + 256;                // 64
    int*   mcnt = (int*)(e0 + 64);        // 20*2048
    int*   midx = mcnt + STEPS * N_AG;    // 20*2048*CAP

    k_init<<<1138, 256, 0, stream>>>(h_in, c_in, Wsoc, bsoc, bih, bhh, Wih, Whh,
                                     h0, cb, We, bc, e0, whF, wlF, out + 20 * N_AG * 2);
    k_gridmatch<<<STEPS, 256, 0, stream>>>(X, masks, mcnt, midx);

    for (int t = 0; t < STEPS; t++) {
        // r-input: obs frames (t<=9) use X[t]; frame 10 uses X[10]; t>=11 uses out[t-2]
        const float* rsrc = (t <= 10) ? (X + t * N_AG * 2) : (out + (t - 2) * N_AG * 2);
        float* hp = (t & 1) ? h1 : h0;
        float* hn = (t & 1) ? h0 : h1;
        k_step<<<N_AG / 16, 64, 0, stream>>>(t, rsrc, masks, Win, bin, bsoc, Wout, bout,
                                             We, e0, bc, whF, wlF, mcnt, midx, hp, hn, cb, out);
    }
}

// Round 4
// 302.897 us; speedup vs baseline: 35.7783x; 35.7783x over previous
//
#include <hip/hip_runtime.h>
#include <math.h>

// ---------------------------------------------------------------------------
// SocialLstm: T=24, N=2048, INPUT_DIM=2, HIDDEN=64, MEDIATE=128, SOCIAL=64,
// OUT_DIM=2, N_SIZE=2, CELL=0.3, T_obs=9, T_pred=19, WIN=9.
//
// R4: k_step restructured after R3's latency collapse (128 waves total, serial
// z-prep, per-wave 256 global loads -> 589us/step). Now: 512 thr x 128 blocks
// (1024 waves, 2/SIMD), block = 16 agents, cooperative z-build into LDS as
// bf16 hi/lo planes in A-fragment order (1 ds_read_b128 per frag), wave = 2
// ntiles (48 MFMA, 32 coalesced W uint4 loads, fully unrolled). MFMA hi/lo
// split (ZhWh+ZlWh+ZhWl) verified correct in R3 (absmax 1.95e-3).
// ---------------------------------------------------------------------------

#define N_AG   2048
#define HID    64
#define STEPS  20
#define CAP    12

typedef short short8 __attribute__((ext_vector_type(8)));
typedef float f32x4  __attribute__((ext_vector_type(4)));
union FU { uint4 q; short8 v; };

__device__ __forceinline__ unsigned short bf16rne(float x) {
    unsigned u = __float_as_uint(x);
    unsigned r = (u + 0x7fff + ((u >> 16) & 1)) >> 16;
    return (unsigned short)r;
}

// ---------------------------------------------------------------------------
// k_init: copy h0/c, zero tail frames, We (64x64 folded Wsoc), bc, and
// fragment-ordered bf16 hi/lo packs of Wc = [W_ih | W_hh] (256x256):
// whF/wlF[(nt*8+kt)*64 + lane]: gate g = nt*16+(lane&15),
// k = kt*32 + (lane>>4)*8 + j.   (verified by R3 pass)
// ---------------------------------------------------------------------------
__global__ void k_init(const float* __restrict__ h_in, const float* __restrict__ c_in,
                       const float* __restrict__ Wsoc,
                       const float* __restrict__ bih, const float* __restrict__ bhh,
                       const float* __restrict__ Wih, const float* __restrict__ Whh,
                       float* __restrict__ h0, float* __restrict__ cbuf,
                       float* __restrict__ We, float* __restrict__ bc,
                       uint4* __restrict__ whF, uint4* __restrict__ wlF,
                       float* __restrict__ otail)
{
    int idx = blockIdx.x * 256 + threadIdx.x;
    if (idx < 131072) { h0[idx] = h_in[idx]; return; }
    idx -= 131072;
    if (idx < 131072) { cbuf[idx] = c_in[idx]; return; }
    idx -= 131072;
    if (idx < 16384)  { otail[idx] = 0.f; return; }   // frames 20..23 of d_out
    idx -= 16384;
    if (idx < 4096) {
        int s = idx >> 6, k = idx & 63;
        float a = 0.f;
        #pragma unroll
        for (int w = 0; w < 9; w++) a += Wsoc[s * 576 + w * 64 + k];
        We[idx] = a; return;
    }
    idx -= 4096;
    if (idx < 256) { bc[idx] = bih[idx] + bhh[idx]; return; }
    idx -= 256;
    if (idx < 8192) {
        int nt = idx >> 9, rem = idx & 511, kt = rem >> 6, ln = rem & 63;
        int g  = nt * 16 + (ln & 15);
        int k0 = kt * 32 + (ln >> 4) * 8;
        unsigned uh[4], ul[4];
        #pragma unroll
        for (int w = 0; w < 4; w++) {
            int k = k0 + 2 * w;
            float a = (k < 192)     ? Wih[g * 192 + k]       : Whh[g * 64 + (k - 192)];
            float b = (k + 1 < 192) ? Wih[g * 192 + k + 1]   : Whh[g * 64 + (k + 1 - 192)];
            unsigned short ha = bf16rne(a), hb = bf16rne(b);
            float fa = __uint_as_float(((unsigned)ha) << 16);
            float fb = __uint_as_float(((unsigned)hb) << 16);
            unsigned short la = bf16rne(a - fa), lb = bf16rne(b - fb);
            uh[w] = (unsigned)ha | ((unsigned)hb << 16);
            ul[w] = (unsigned)la | ((unsigned)lb << 16);
        }
        whF[idx] = make_uint4(uh[0], uh[1], uh[2], uh[3]);
        wlF[idx] = make_uint4(ul[0], ul[1], ul[2], ul[3]);
        return;
    }
}

// ---------------------------------------------------------------------------
// k_gridmatch: one block per step t. Exact fp32 key calc, O(N) hash match.
// Masked agents (key 0) excluded from insert AND probe (kills mega-chain).
// ---------------------------------------------------------------------------
__device__ __forceinline__ int khash(int k) {
    return (int)(((unsigned)k * 2654435761u) >> 21);   // 11-bit bucket
}

__global__ void k_gridmatch(const float* __restrict__ X, const float* __restrict__ masks,
                            int* __restrict__ mcnt, int* __restrict__ midx)
{
    int t = blockIdx.x;
    int tid = threadIdx.x;
    __shared__ float red[256];
    __shared__ int kk[N_AG];
    __shared__ int head[N_AG];
    __shared__ int nxt[N_AG];
    const float* Xt = X + t * N_AG * 2;

    float mnx = 1e30f, mny = 1e30f;
    for (int i = tid; i < N_AG; i += 256) {
        mnx = fminf(mnx, Xt[2 * i]);
        mny = fminf(mny, Xt[2 * i + 1]);
    }
    red[tid] = mnx; __syncthreads();
    for (int s = 128; s > 0; s >>= 1) { if (tid < s) red[tid] = fminf(red[tid], red[tid + s]); __syncthreads(); }
    float ltx = red[0]; __syncthreads();
    red[tid] = mny; __syncthreads();
    for (int s = 128; s > 0; s >>= 1) { if (tid < s) red[tid] = fminf(red[tid], red[tid + s]); __syncthreads(); }
    float lty = red[0]; __syncthreads();

    ltx -= 1.2f;   // margin = 2*N_SIZE*CELL
    lty -= 1.2f;

    for (int i = tid; i < N_AG; i += 256) {
        float m = masks[t * N_AG + i];
        int px = (int)floorf((Xt[2 * i]     - ltx) / 0.3f);
        int py = (int)floorf((Xt[2 * i + 1] - lty) / 0.3f);
        int im = (int)m;
        px *= im; py *= im;
        kk[i] = px * 65536 + py;   // masked -> 0; real agents have px,py >= 4
        head[i] = -1;
    }
    __syncthreads();

    for (int j = tid; j < N_AG; j += 256) {
        int kj = kk[j];
        if (kj != 0) {
            int h = khash(kj);
            nxt[j] = atomicExch(&head[h], j);
        }
    }
    __syncthreads();

    for (int i = tid; i < N_AG; i += 256) {
        int ki = kk[i];
        int cnt = 0;
        int base = (t * N_AG + i) * CAP;
        if (ki != 0) {
            int tkey = ki - 65537;
            int lst[CAP];
            for (int j = head[khash(tkey)]; j >= 0; j = nxt[j]) {
                if (kk[j] == tkey) { if (cnt < CAP) lst[cnt] = j; cnt++; }
            }
            if (cnt > CAP) cnt = CAP;
            for (int a = 1; a < cnt; a++) {           // ascending j = ref sum order
                int v = lst[a]; int b = a - 1;
                while (b >= 0 && lst[b] > v) { lst[b + 1] = lst[b]; b--; }
                lst[b + 1] = v;
            }
            for (int a = 0; a < cnt; a++) midx[base + a] = lst[a];
        }
        mcnt[t * N_AG + i] = cnt;
    }
}

// ---------------------------------------------------------------------------
// k_step: one recurrence step. 128 blocks x 512 threads (8 waves).
// Block = 16 agents. Phases (barrier between each):
//  A: cv gather (32 thr/agent) -> cvs[16][64]        (only cnt>0 agents)
//  B: z-build: all 256 cols per agent (r | e | h), fp32 -> bf16 hi/lo,
//     stored in A-FRAGMENT ORDER: plane[((kt*4+quad)*16+m)*8 + jj]
//  C: GEMM: wave w -> ntiles {2w, 2w+1}; per kt: 2 ds_read_b128 (A hi/lo) +
//     4 global uint4 (W hi/lo x2) + 6 MFMA. acc -> gbuf LDS.
//  D: LSTM elementwise (512 thr x 2 items) -> cbuf/hnext global, hs LDS
//  E: out = (h @ W_out.T + b_out) * mask  (32 threads)
// ---------------------------------------------------------------------------
__global__ __launch_bounds__(512) void k_step(
    int t,
    const float* __restrict__ rsrc,      // [N,2]: X[t] (t<=10) or out[t-2]
    const float* __restrict__ masks,
    const float* __restrict__ Win, const float* __restrict__ bin,
    const float* __restrict__ bsoc,
    const float* __restrict__ Wout, const float* __restrict__ bout,
    const float* __restrict__ We, const float* __restrict__ bc,
    const uint4* __restrict__ whF, const uint4* __restrict__ wlF,
    const int* __restrict__ mcnt, const int* __restrict__ midx,
    const float* __restrict__ hprev, float* __restrict__ hnext,
    float* __restrict__ cbuf, float* __restrict__ out)
{
    __shared__ __align__(16) short zsh[4096];   // [(kt*4+quad)*16+m]*8+jj
    __shared__ __align__(16) short zsl[4096];
    __shared__ float gbuf[16][258];
    __shared__ float cvs[16][64];
    __shared__ float hs[16][66];

    const int tid   = threadIdx.x;
    const int wbase = blockIdx.x * 16;

    // ---- phase A: cv gather; 32 threads per agent ----
    {
        int m  = tid >> 5;          // agent slot 0..15
        int j  = tid & 31;
        int agent = wbase + m;
        int cnt = mcnt[t * N_AG + agent];
        if (cnt > 0) {
            int base = (t * N_AG + agent) * CAP;
            float c0 = 0.f, c1 = 0.f;
            for (int n = 0; n < cnt; n++) {
                int r = midx[base + n];
                c0 += hprev[r * HID + j];
                c1 += hprev[r * HID + j + 32];
            }
            cvs[m][j]      = c0;
            cvs[m][j + 32] = c1;
        }
    }
    __syncthreads();

    // ---- phase B: z-build (cols of z = [r(128)|e(64)|h(64)]) ----
    {
        int m  = tid >> 5;
        int s5 = tid & 31;
        int agent = wbase + m;
        float px = rsrc[2 * agent], py = rsrc[2 * agent + 1];
        int cnt = mcnt[t * N_AG + agent];
        int quad = s5 >> 3, jj = s5 & 7;

        #pragma unroll
        for (int u = 0; u < 8; u++) {
            int c = 32 * u + s5;
            float v;
            if (u < 4) {                       // r-cols
                v = fmaxf(Win[2 * c] * px + Win[2 * c + 1] * py + bin[c], 0.f);
            } else if (u < 6) {                // e-cols
                int s = c - 128;
                float acc = bsoc[s];
                if (cnt > 0) {                 // cnt>0 implies mask==1
                    const float* wp = &We[s * 64];
                    #pragma unroll 4
                    for (int k = 0; k < 64; k += 4) {
                        float4 c4 = *(const float4*)&cvs[m][k];
                        float4 w4 = *(const float4*)&wp[k];
                        acc += c4.x * w4.x + c4.y * w4.y + c4.z * w4.z + c4.w * w4.w;
                    }
                }
                v = fmaxf(acc, 0.f);
            } else {                           // h-cols
                v = hprev[agent * HID + (c - 192)];
            }
            unsigned short h = bf16rne(v);
            float fh = __uint_as_float(((unsigned)h) << 16);
            unsigned short l = bf16rne(v - fh);
            int fi = ((u * 4 + quad) * 16 + m) * 8 + jj;   // kt = u
            zsh[fi] = (short)h;
            zsl[fi] = (short)l;
        }
    }
    __syncthreads();

    // ---- phase C: GEMM; wave w -> ntiles 2w, 2w+1 ----
    {
        const int wv   = tid >> 6;
        const int lane = tid & 63;
        const int mA   = lane & 15, quad = lane >> 4;
        const int nt0  = 2 * wv;

        const uint4* zhp = (const uint4*)zsh;   // frag = [(kt*4+quad)*16+mA]
        const uint4* zlp = (const uint4*)zsl;
        const uint4* wh0 = whF + (nt0 * 8) * 64 + lane;
        const uint4* wl0 = wlF + (nt0 * 8) * 64 + lane;

        f32x4 a0 = {0.f, 0.f, 0.f, 0.f};
        f32x4 a1 = {0.f, 0.f, 0.f, 0.f};
        #pragma unroll
        for (int kt = 0; kt < 8; kt++) {
            FU az, bz, w0h, w0l, w1h, w1l;
            int fi = (kt * 4 + quad) * 16 + mA;
            az.q  = zhp[fi];
            bz.q  = zlp[fi];
            w0h.q = wh0[kt * 64];
            w0l.q = wl0[kt * 64];
            w1h.q = wh0[(8 + kt) * 64];
            w1l.q = wl0[(8 + kt) * 64];
            a0 = __builtin_amdgcn_mfma_f32_16x16x32_bf16(az.v, w0h.v, a0, 0, 0, 0);
            a1 = __builtin_amdgcn_mfma_f32_16x16x32_bf16(az.v, w1h.v, a1, 0, 0, 0);
            a0 = __builtin_amdgcn_mfma_f32_16x16x32_bf16(bz.v, w0h.v, a0, 0, 0, 0);
            a1 = __builtin_amdgcn_mfma_f32_16x16x32_bf16(bz.v, w1h.v, a1, 0, 0, 0);
            a0 = __builtin_amdgcn_mfma_f32_16x16x32_bf16(az.v, w0l.v, a0, 0, 0, 0);
            a1 = __builtin_amdgcn_mfma_f32_16x16x32_bf16(az.v, w1l.v, a1, 0, 0, 0);
        }
        // C-layout: row = quad*4 + r (agent), col = lane&15 (gate in tile)
        const int colA = lane & 15;
        #pragma unroll
        for (int r = 0; r < 4; r++) {
            int row = quad * 4 + r;
            gbuf[row][nt0 * 16 + colA]       = a0[r];
            gbuf[row][(nt0 + 1) * 16 + colA] = a1[r];
        }
    }
    __syncthreads();

    // ---- phase D: LSTM elementwise; 2 items per thread ----
    #pragma unroll
    for (int it = 0; it < 2; it++) {
        int item = tid + it * 512;
        int m = item >> 6, hid = item & 63;
        int agent = wbase + m;
        float gi = gbuf[m][hid]        + bc[hid];
        float gf = gbuf[m][64 + hid]   + bc[64 + hid];
        float gg = gbuf[m][128 + hid]  + bc[128 + hid];
        float go = gbuf[m][192 + hid]  + bc[192 + hid];
        float cp = cbuf[agent * HID + hid];
        float si = 1.f / (1.f + expf(-gi));
        float sf = 1.f / (1.f + expf(-gf));
        float so = 1.f / (1.f + expf(-go));
        float cn = sf * cp + si * tanhf(gg);
        float hn = so * tanhf(cn);
        cbuf[agent * HID + hid]  = cn;
        hnext[agent * HID + hid] = hn;
        hs[m][hid] = hn;
    }
    __syncthreads();

    // ---- phase E: out = (h @ W_out.T + b_out) * mask ----
    if (tid < 32) {
        int m = tid >> 1, d = tid & 1;
        int agent = wbase + m;
        float acc = bout[d];
        #pragma unroll 4
        for (int k = 0; k < 64; k += 4) {
            float4 h4 = *(const float4*)&hs[m][k];
            float4 w4 = *(const float4*)&Wout[d * 64 + k];
            acc += h4.x * w4.x + h4.y * w4.y + h4.z * w4.z + h4.w * w4.w;
        }
        out[(t * N_AG + agent) * 2 + d] = acc * masks[t * N_AG + agent];
    }
}

// ---------------------------------------------------------------------------
extern "C" void kernel_launch(void* const* d_in, const int* in_sizes, int n_in,
                              void* d_out, int out_size, void* d_ws, size_t ws_size,
                              hipStream_t stream)
{
    const float* X     = (const float*)d_in[0];
    const float* masks = (const float*)d_in[1];
    const float* h_in  = (const float*)d_in[2];
    const float* c_in  = (const float*)d_in[3];
    // d_in[4] = Y (unused), d_in[5] = T_obs (=9), d_in[6] = T_pred (=19)
    const float* Win   = (const float*)d_in[7];
    const float* bin   = (const float*)d_in[8];
    const float* Wsoc  = (const float*)d_in[9];
    const float* bsoc  = (const float*)d_in[10];
    const float* Wih   = (const float*)d_in[11];
    const float* Whh   = (const float*)d_in[12];
    const float* bih   = (const float*)d_in[13];
    const float* bhh   = (const float*)d_in[14];
    const float* Wout  = (const float*)d_in[15];
    const float* bout  = (const float*)d_in[16];
    float* out = (float*)d_out;

    // workspace layout (uint4-aligned first)
    uint4* whF = (uint4*)d_ws;            // 8192
    uint4* wlF = whF + 8192;              // 8192
    float* h0  = (float*)(wlF + 8192);    // 131072
    float* h1  = h0 + 131072;             // 131072
    float* cb  = h1 + 131072;             // 131072
    float* We  = cb + 131072;             // 4096
    float* bc  = We + 4096;               // 256
    int*   mcnt = (int*)(bc + 256);       // 20*2048
    int*   midx = mcnt + STEPS * N_AG;    // 20*2048*CAP

    k_init<<<1137, 256, 0, stream>>>(h_in, c_in, Wsoc, bih, bhh, Wih, Whh,
                                     h0, cb, We, bc, whF, wlF, out + 20 * N_AG * 2);
    k_gridmatch<<<STEPS, 256, 0, stream>>>(X, masks, mcnt, midx);

    for (int t = 0; t < STEPS; t++) {
        // r-input: obs frames (t<=9) use X[t]; frame 10 uses X[10]; t>=11 uses out[t-2]
        const float* rsrc = (t <= 10) ? (X + t * N_AG * 2) : (out + (t - 2) * N_AG * 2);
        float* hp = (t & 1) ? h1 : h0;
        float* hn = (t & 1) ? h0 : h1;
        k_step<<<N_AG / 16, 512, 0, stream>>>(t, rsrc, masks, Win, bin, bsoc, Wout, bout,
                                              We, bc, whF, wlF, mcnt, midx, hp, hn, cb, out);
    }
}